// Round 5
// baseline (645.765 us; speedup 1.0000x reference)
//
#include <hip/hip_runtime.h>
#include <hip/hip_bf16.h>

#define D_IN  128
#define D_HID 16
#define N_CLS 2
#define NSEG  16           // cursor/histogram privatization segments
#define SEGOF(e) (((e) >> 8) & (NSEG - 1))

#define FE 0   // edge_index storage: 0 = int32, 1 = int64

// ---------------- edge dtype detection (1 block) ----------------
__global__ void k_detect(const int* __restrict__ ev, int* __restrict__ flags) {
    __shared__ int sE;
    if (threadIdx.x == 0) sE = 0;
    __syncthreads();
    if (ev[2 * threadIdx.x + 1] != 0) atomicOr(&sE, 1);
    __syncthreads();
    if (threadIdx.x == 0) flags[FE] = sE ? 0 : 1;
}

template<bool I64>
__device__ __forceinline__ int lde(const void* p, size_t i) {
    if constexpr (I64) return (int)((const long long*)p)[i];
    else               return ((const int*)p)[i];
}

// ---------------- segmented degree histogram ----------------
template<bool I64>
__global__ void k_seg_count(const void* __restrict__ ei, unsigned int* __restrict__ cnt,
                            int E, int n, const int* __restrict__ flags) {
    if (flags[FE] != (int)I64) return;
    int e = blockIdx.x * blockDim.x + threadIdx.x;
    if (e >= E) return;
    int d = lde<I64>(ei, (size_t)E + e);
    atomicAdd(&cnt[(size_t)SEGOF(e) * n + d], 1u);
}

// ---------------- scans: deg total + dinv + row_ptr + cursors ----------------
// scan1: t[i] = sum_g cnt[g][i]; dinv = rsqrt(t+1); block-inclusive-scan t.
__global__ void k_scan1(const unsigned int* __restrict__ cnt, float* __restrict__ dinv,
                        int* __restrict__ row_ptr, int* __restrict__ bsums, int n) {
    __shared__ int s[256];
    int tid = threadIdx.x;
    int i = blockIdx.x * 256 + tid;
    int t = 0;
    if (i < n) {
#pragma unroll
        for (int g = 0; g < NSEG; ++g) t += (int)cnt[(size_t)g * n + i];
        dinv[i] = rsqrtf((float)(t + 1));   // +1 self loop
    }
    s[tid] = t;
    __syncthreads();
#pragma unroll
    for (int off = 1; off < 256; off <<= 1) {
        int v = (tid >= off) ? s[tid - off] : 0;
        __syncthreads();
        s[tid] += v;
        __syncthreads();
    }
    if (i < n) row_ptr[i + 1] = s[tid];
    if (tid == 255) bsums[blockIdx.x] = s[255];
}

// scan2: single 1024-block exclusive scan of block sums.
__global__ void k_scan2(int* __restrict__ bsums, int nb) {
    __shared__ int s[1024];
    int tid = threadIdx.x;
    int v = (tid < nb) ? bsums[tid] : 0;
    s[tid] = v;
    __syncthreads();
#pragma unroll
    for (int off = 1; off < 1024; off <<= 1) {
        int t = (tid >= off) ? s[tid - off] : 0;
        __syncthreads();
        s[tid] += t;
        __syncthreads();
    }
    if (tid < nb) bsums[tid] = s[tid] - v;   // exclusive
}

// scan3: finalize row_ptr; convert cnt -> per-(segment,node) cursor starts in place.
__global__ void k_scan3(int* __restrict__ row_ptr, const int* __restrict__ bsums,
                        unsigned int* __restrict__ cnt, int n) {
    int i = blockIdx.x * 256 + threadIdx.x;
    if (i >= n) return;
    int end = row_ptr[i + 1] + bsums[blockIdx.x];
    row_ptr[i + 1] = end;
    if (i == 0) row_ptr[0] = 0;
    int c[NSEG], t = 0;
#pragma unroll
    for (int g = 0; g < NSEG; ++g) { c[g] = (int)cnt[(size_t)g * n + i]; t += c[g]; }
    int run = end - t;
#pragma unroll
    for (int g = 0; g < NSEG; ++g) { cnt[(size_t)g * n + i] = (unsigned int)run; run += c[g]; }
}

// ---------------- fill: deterministic segment, privatized cursors ----------------
template<bool I64>
__global__ void k_fill(const void* __restrict__ ei, unsigned int* __restrict__ cursor,
                       int* __restrict__ csr_src, int E, int n, const int* __restrict__ flags) {
    if (flags[FE] != (int)I64) return;
    int e = blockIdx.x * blockDim.x + threadIdx.x;
    if (e >= E) return;
    int s = lde<I64>(ei, (size_t)e);
    int d = lde<I64>(ei, (size_t)E + e);
    unsigned int pos = atomicAdd(&cursor[(size_t)SEGOF(e) * n + d], 1u);
    __builtin_nontemporal_store(s, &csr_src[pos]);
}

// ---------------- layer 1 GEMM: g1 = dinv * (x @ W1) ----------------
__global__ void k_gemm1(const float* __restrict__ x, const float* __restrict__ W1,
                        const float* __restrict__ dinv, float* __restrict__ g1, int n) {
    __shared__ float w[D_IN * D_HID];  // 8 KiB
    for (int i = threadIdx.x; i < D_IN * D_HID; i += blockDim.x)
        w[i] = W1[i];
    __syncthreads();
    int tid = blockIdx.x * blockDim.x + threadIdx.x;
    int node = tid >> 4, f = tid & 15;
    if (node >= n) return;
    const float4* xr = (const float4*)(x + (size_t)node * D_IN);
    float acc = 0.f;
#pragma unroll
    for (int k4 = 0; k4 < D_IN / 4; ++k4) {
        float4 v = xr[k4];
        int k = k4 * 4;
        acc += v.x * w[(k + 0) * D_HID + f];
        acc += v.y * w[(k + 1) * D_HID + f];
        acc += v.z * w[(k + 2) * D_HID + f];
        acc += v.w * w[(k + 3) * D_HID + f];
    }
    g1[tid] = dinv[node] * acc;
}

// ---------------- fused: gather-agg1 + bias + ReLU + GEMM2 -> g2 ----------------
__global__ void k_agg1f(const int* __restrict__ csr_src, const int* __restrict__ row_ptr,
                        const float* __restrict__ dinv, const float* __restrict__ g1,
                        const float* __restrict__ b1, const float* __restrict__ W2,
                        float2* __restrict__ g2, int n) {
    int tid = blockIdx.x * blockDim.x + threadIdx.x;
    int node = tid >> 4, f = tid & 15;
    if (node >= n) return;
    int beg = row_ptr[node], end = row_ptr[node + 1];
    float acc = g1[(size_t)node * D_HID + f];   // self-loop term
    int gbase = (threadIdx.x & 63) & 48;
    for (int j = beg; j < end; j += 16) {
        int m = end - j; if (m > 16) m = 16;
        int myS = (j + f < end) ? csr_src[j + f] : 0;
        for (int k = 0; k < m; ++k) {
            int s = __shfl(myS, gbase + k, 64);
            acc += g1[(size_t)s * D_HID + f];
        }
    }
    float di = dinv[node];
    float r = fmaxf(b1[f] + di * acc, 0.f);
    float c0 = r * W2[f * N_CLS + 0];
    float c1 = r * W2[f * N_CLS + 1];
#pragma unroll
    for (int m = 8; m >= 1; m >>= 1) {
        c0 += __shfl_xor(c0, m, 64);
        c1 += __shfl_xor(c1, m, 64);
    }
    if (f == 0) g2[node] = make_float2(di * c0, di * c1);
}

// ---------------- fused: gather-agg2 + bias + log_softmax -> out ----------------
__global__ void k_agg2lsm(const int* __restrict__ csr_src, const int* __restrict__ row_ptr,
                          const float* __restrict__ dinv, const float2* __restrict__ g2,
                          const float* __restrict__ b2, float2* __restrict__ out, int n) {
    int node = blockIdx.x * blockDim.x + threadIdx.x;
    if (node >= n) return;
    float2 self = g2[node];
    float a0 = self.x, a1 = self.y;
    int beg = row_ptr[node], end = row_ptr[node + 1];
    for (int j = beg; j < end; ++j) {
        float2 t = g2[csr_src[j]];
        a0 += t.x; a1 += t.y;
    }
    float di = dinv[node];
    float v0 = b2[0] + di * a0;
    float v1 = b2[1] + di * a1;
    float mx = fmaxf(v0, v1);
    float lse = mx + logf(expf(v0 - mx) + expf(v1 - mx));
    out[node] = make_float2(v0 - lse, v1 - lse);
}

// =================== fallback (round-3 atomic path, if ws too small) ===================
__global__ void fb_deg_init(unsigned int* __restrict__ deg, int n) {
    int i = blockIdx.x * blockDim.x + threadIdx.x;
    if (i < n) deg[i] = 1u;
}
template<bool I64>
__global__ void fb_deg_count(const void* __restrict__ ei, unsigned int* __restrict__ deg,
                             int E, const int* __restrict__ flags) {
    if (flags[FE] != (int)I64) return;
    int e = blockIdx.x * blockDim.x + threadIdx.x;
    if (e < E) atomicAdd(&deg[lde<I64>(ei, (size_t)E + e)], 1u);
}
__global__ void fb_dinv_inplace(float* __restrict__ dinv, int n) {
    int i = blockIdx.x * blockDim.x + threadIdx.x;
    if (i < n) {
        unsigned int u = ((const unsigned int*)dinv)[i];
        dinv[i] = rsqrtf((float)u);
    }
}
__global__ void fb_a1_init(const float* __restrict__ h1, const float* __restrict__ dinv,
                           const float* __restrict__ b1, float* __restrict__ a1, int n) {
    int tid = blockIdx.x * blockDim.x + threadIdx.x;
    if (tid >= n * D_HID) return;
    int node = tid >> 4, f = tid & 15;
    float di = dinv[node];
    a1[tid] = b1[f] + di * di * h1[tid];
}
template<bool I64>
__global__ void fb_agg1(const void* __restrict__ ei, const float* __restrict__ dinv,
                        const float* __restrict__ h1, float* __restrict__ a1,
                        int E, const int* __restrict__ flags) {
    if (flags[FE] != (int)I64) return;
    int tid = blockIdx.x * blockDim.x + threadIdx.x;
    int e = tid >> 4, f = tid & 15;
    if (e >= E) return;
    int s = lde<I64>(ei, (size_t)e);
    int d = lde<I64>(ei, (size_t)E + e);
    float norm = dinv[s] * dinv[d];
    atomicAdd(&a1[(size_t)d * D_HID + f], h1[(size_t)s * D_HID + f] * norm);
}
__global__ void fb_relu_gemm2(const float* __restrict__ a1, const float* __restrict__ W2,
                              float* __restrict__ h2, int n) {
    int node = blockIdx.x * blockDim.x + threadIdx.x;
    if (node >= n) return;
    float c0 = 0.f, c1 = 0.f;
    const float* row = a1 + (size_t)node * D_HID;
#pragma unroll
    for (int f = 0; f < D_HID; ++f) {
        float r = fmaxf(row[f], 0.f);
        c0 += r * W2[f * N_CLS + 0];
        c1 += r * W2[f * N_CLS + 1];
    }
    h2[(size_t)node * 2 + 0] = c0;
    h2[(size_t)node * 2 + 1] = c1;
}
__global__ void fb_a2_init(const float* __restrict__ h2, const float* __restrict__ dinv,
                           const float* __restrict__ b2, float* __restrict__ a2, int n) {
    int tid = blockIdx.x * blockDim.x + threadIdx.x;
    if (tid >= n * N_CLS) return;
    int node = tid >> 1, c = tid & 1;
    float di = dinv[node];
    a2[tid] = b2[c] + di * di * h2[tid];
}
template<bool I64>
__global__ void fb_agg2(const void* __restrict__ ei, const float* __restrict__ dinv,
                        const float* __restrict__ h2, float* __restrict__ a2,
                        int E, const int* __restrict__ flags) {
    if (flags[FE] != (int)I64) return;
    int e = blockIdx.x * blockDim.x + threadIdx.x;
    if (e >= E) return;
    int s = lde<I64>(ei, (size_t)e);
    int d = lde<I64>(ei, (size_t)E + e);
    float norm = dinv[s] * dinv[d];
    atomicAdd(&a2[(size_t)d * 2 + 0], h2[(size_t)s * 2 + 0] * norm);
    atomicAdd(&a2[(size_t)d * 2 + 1], h2[(size_t)s * 2 + 1] * norm);
}
__global__ void fb_gemm1(const float* __restrict__ x, const float* __restrict__ W1,
                         float* __restrict__ h1, int n) {
    __shared__ float w[D_IN * D_HID];
    for (int i = threadIdx.x; i < D_IN * D_HID; i += blockDim.x) w[i] = W1[i];
    __syncthreads();
    int tid = blockIdx.x * blockDim.x + threadIdx.x;
    int node = tid >> 4, f = tid & 15;
    if (node >= n) return;
    const float4* xr = (const float4*)(x + (size_t)node * D_IN);
    float acc = 0.f;
#pragma unroll
    for (int k4 = 0; k4 < D_IN / 4; ++k4) {
        float4 v = xr[k4];
        int k = k4 * 4;
        acc += v.x * w[(k + 0) * D_HID + f];
        acc += v.y * w[(k + 1) * D_HID + f];
        acc += v.z * w[(k + 2) * D_HID + f];
        acc += v.w * w[(k + 3) * D_HID + f];
    }
    h1[tid] = acc;
}
__global__ void fb_lsm(const float* __restrict__ a2, float* __restrict__ out, int n) {
    int node = blockIdx.x * blockDim.x + threadIdx.x;
    if (node >= n) return;
    float v0 = a2[(size_t)node * 2 + 0];
    float v1 = a2[(size_t)node * 2 + 1];
    float m = fmaxf(v0, v1);
    float lse = m + logf(expf(v0 - m) + expf(v1 - m));
    out[(size_t)node * 2 + 0] = v0 - lse;
    out[(size_t)node * 2 + 1] = v1 - lse;
}

extern "C" void kernel_launch(void* const* d_in, const int* in_sizes, int n_in,
                              void* d_out, int out_size, void* d_ws, size_t ws_size,
                              hipStream_t stream) {
    const float* x  = (const float*)d_in[0];
    const void*  ei = d_in[1];
    const float* W1 = (const float*)d_in[2];
    const float* b1 = (const float*)d_in[3];
    const float* W2 = (const float*)d_in[4];
    const float* b2 = (const float*)d_in[5];

    const int N = in_sizes[0] / D_IN;      // 100000
    const int E = in_sizes[1] / 2;         // 3200000

    const int B = 256;
    dim3 blk(B);
    const int nBlkN = (N + B - 1) / B;     // 391
    const int nBlkE = (E + B - 1) / B;
    char* ws = (char*)d_ws;

    // CSR-path workspace layout (bytes, 128-aligned)
    const size_t oDinv = 0;                                // N f32
    const size_t oRow  = 400128;                           // (N+1) int
    const size_t oBsum = 800512;                           // 1024 int
    const size_t oCsr  = 804608;                           // E int
    const size_t oX    = oCsr + (size_t)E * 4;             // union{ cnt[16][N] u32 | g1 N*16 f32 + g2 N*2 f32 }
    const size_t xSize = (size_t)NSEG * N * 4;             // 6.4MB (== g1 size)
    const size_t oG2   = oX + (size_t)N * D_HID * 4;       // after g1
    const size_t oFlag = oX + xSize + (size_t)N * 2 * 4;   // past union max
    const size_t needCSR = oFlag + 128;

    if (ws_size >= needCSR && nBlkN <= 1024) {
        float*        dinv    = (float*)(ws + oDinv);
        int*          row_ptr = (int*)(ws + oRow);
        int*          bsums   = (int*)(ws + oBsum);
        int*          csr_src = (int*)(ws + oCsr);
        unsigned int* cnt     = (unsigned int*)(ws + oX);  // later: cursors; later: g1 aliases
        float*        g1      = (float*)(ws + oX);
        float2*       g2      = (float2*)(ws + oG2);
        int*          flags   = (int*)(ws + oFlag);

        k_detect<<<dim3(1), blk, 0, stream>>>((const int*)ei, flags);

        hipMemsetAsync(cnt, 0, (size_t)NSEG * N * 4, stream);
        k_seg_count<false><<<dim3(nBlkE), blk, 0, stream>>>(ei, cnt, E, N, flags);
        k_seg_count<true ><<<dim3(nBlkE), blk, 0, stream>>>(ei, cnt, E, N, flags);

        k_scan1<<<dim3(nBlkN), blk, 0, stream>>>(cnt, dinv, row_ptr, bsums, N);
        k_scan2<<<dim3(1), dim3(1024), 0, stream>>>(bsums, nBlkN);
        k_scan3<<<dim3(nBlkN), blk, 0, stream>>>(row_ptr, bsums, cnt, N);

        k_fill<false><<<dim3(nBlkE), blk, 0, stream>>>(ei, cnt, csr_src, E, N, flags);
        k_fill<true ><<<dim3(nBlkE), blk, 0, stream>>>(ei, cnt, csr_src, E, N, flags);

        dim3 g_nh((N * D_HID + B - 1) / B);
        k_gemm1<<<g_nh, blk, 0, stream>>>(x, W1, dinv, g1, N);   // overwrites cursor region (dead)
        k_agg1f<<<g_nh, blk, 0, stream>>>(csr_src, row_ptr, dinv, g1, b1, W2, g2, N);
        k_agg2lsm<<<dim3(nBlkN), blk, 0, stream>>>(csr_src, row_ptr, dinv, g2, b2,
                                                   (float2*)d_out, N);
    } else {
        // fallback: round-3 atomic path (needs ~14.8 MB)
        float* dinv  = (float*)(ws + 0);
        float* h1    = (float*)(ws + 400128);
        float* a1    = (float*)(ws + 6800256);
        float* h2    = (float*)(ws + 13200384);
        float* a2    = (float*)(ws + 14000512);
        int*   flags = (int*)  (ws + 14800640);

        k_detect<<<dim3(1), blk, 0, stream>>>((const int*)ei, flags);
        fb_deg_init<<<dim3(nBlkN), blk, 0, stream>>>((unsigned int*)dinv, N);
        fb_deg_count<false><<<dim3(nBlkE), blk, 0, stream>>>(ei, (unsigned int*)dinv, E, flags);
        fb_deg_count<true ><<<dim3(nBlkE), blk, 0, stream>>>(ei, (unsigned int*)dinv, E, flags);
        fb_dinv_inplace<<<dim3(nBlkN), blk, 0, stream>>>(dinv, N);

        dim3 g_nh((N * D_HID + B - 1) / B);
        fb_gemm1<<<g_nh, blk, 0, stream>>>(x, W1, h1, N);
        fb_a1_init<<<g_nh, blk, 0, stream>>>(h1, dinv, b1, a1, N);
        dim3 g_eh(((size_t)E * D_HID + B - 1) / B);
        fb_agg1<false><<<g_eh, blk, 0, stream>>>(ei, dinv, h1, a1, E, flags);
        fb_agg1<true ><<<g_eh, blk, 0, stream>>>(ei, dinv, h1, a1, E, flags);
        fb_relu_gemm2<<<dim3(nBlkN), blk, 0, stream>>>(a1, W2, h2, N);
        dim3 g_n2((N * N_CLS + B - 1) / B);
        fb_a2_init<<<g_n2, blk, 0, stream>>>(h2, dinv, b2, a2, N);
        fb_agg2<false><<<dim3(nBlkE), blk, 0, stream>>>(ei, dinv, h2, a2, E, flags);
        fb_agg2<true ><<<dim3(nBlkE), blk, 0, stream>>>(ei, dinv, h2, a2, E, flags);
        fb_lsm<<<dim3(nBlkN), blk, 0, stream>>>(a2, (float*)d_out, N);
    }
}

// Round 6
// 294.274 us; speedup vs baseline: 2.1944x; 2.1944x over previous
//
#include <hip/hip_runtime.h>
#include <hip/hip_bf16.h>

#define D_IN  128
#define D_HID 16
#define N_CLS 2
#define NPB   256          // nodes per bucket (bucket = dst >> 8)
#define MAXB  512          // LDS-side max buckets (supports N <= 131072)
#define TILE  8192         // edges per k_part workgroup
#define CAP   9216         // per-bucket LDS staging capacity (mean 8192, sigma ~90)
#define OVF_CAP 1600000    // overflow scratch capacity (uints, in g1 region)

#define FE 0   // edge_index storage: 0 = int32, 1 = int64

// ---------------- edge dtype detection (1 block) ----------------
__global__ void k_detect(const int* __restrict__ ev, int* __restrict__ flags) {
    __shared__ int sE;
    if (threadIdx.x == 0) sE = 0;
    __syncthreads();
    if (ev[2 * threadIdx.x + 1] != 0) atomicOr(&sE, 1);
    __syncthreads();
    if (threadIdx.x == 0) flags[FE] = sE ? 0 : 1;
}

template<bool I64>
__device__ __forceinline__ int lde(const void* p, size_t i) {
    if constexpr (I64) return (int)((const long long*)p)[i];
    else               return ((const int*)p)[i];
}

// ---------------- bucket histogram (LDS-privatized, grid-stride) ----------------
template<bool I64>
__global__ void k_bhist(const void* __restrict__ ei, unsigned int* __restrict__ gbcnt,
                        int E, const int* __restrict__ flags) {
    if (flags[FE] != (int)I64) return;
    __shared__ unsigned int h[MAXB];
    for (int i = threadIdx.x; i < MAXB; i += blockDim.x) h[i] = 0u;
    __syncthreads();
    int stride = gridDim.x * blockDim.x;
    for (int e = blockIdx.x * blockDim.x + threadIdx.x; e < E; e += stride) {
        int d = lde<I64>(ei, (size_t)E + e);
        atomicAdd(&h[d >> 8], 1u);
    }
    __syncthreads();
    for (int i = threadIdx.x; i < MAXB; i += blockDim.x)
        if (h[i]) atomicAdd(&gbcnt[i], h[i]);   // i < nb whenever h[i] > 0
}

// ---------------- bucket scan: bbase (exclusive) + cursor init ----------------
__global__ void k_bscan(const unsigned int* __restrict__ gbcnt, int* __restrict__ bbase,
                        unsigned int* __restrict__ gcur, int nb) {
    __shared__ int s[MAXB];
    int tid = threadIdx.x;
    int v = (tid < nb) ? (int)gbcnt[tid] : 0;
    s[tid] = v;
    __syncthreads();
#pragma unroll
    for (int off = 1; off < MAXB; off <<= 1) {
        int t = (tid >= off) ? s[tid - off] : 0;
        __syncthreads();
        s[tid] += t;
        __syncthreads();
    }
    int excl = s[tid] - v;
    if (tid <= nb) bbase[tid] = (tid < nb) ? excl : s[nb - 1];  // bbase[nb] = total
    if (tid < nb)  gcur[tid] = (unsigned int)excl;
}

// ---------------- pass 1: LDS-staged partition by bucket ----------------
template<bool I64>
__global__ __launch_bounds__(512) void k_part(
        const void* __restrict__ ei, unsigned int* __restrict__ gcur,
        unsigned int* __restrict__ staged, int E, const int* __restrict__ flags) {
    if (flags[FE] != (int)I64) return;
    __shared__ unsigned int sbuf[TILE];       // 32 KB packed values
    __shared__ unsigned short bbuf[TILE];     // 16 KB bucket ids
    __shared__ int hist[MAXB], scn[MAXB], lbase[MAXB], gb[MAXB];  // 8 KB
    int tid = threadIdx.x;
    int t0 = blockIdx.x * TILE;

    hist[tid] = 0;                            // 512 threads cover MAXB exactly
    __syncthreads();

    int myB[16]; unsigned int myP[16]; int myR[16];
#pragma unroll
    for (int k = 0; k < 16; ++k) {
        int e = t0 + k * 512 + tid;
        if (e < E) {
            int s = lde<I64>(ei, (size_t)e);
            int d = lde<I64>(ei, (size_t)E + e);
            int b = d >> 8;
            myB[k] = b;
            myP[k] = ((unsigned int)s << 8) | (unsigned int)(d & 255);
            myR[k] = atomicAdd(&hist[b], 1);
        } else myB[k] = -1;
    }
    __syncthreads();

    int v = hist[tid];
    scn[tid] = v;
    __syncthreads();
#pragma unroll
    for (int off = 1; off < MAXB; off <<= 1) {
        int t = (tid >= off) ? scn[tid - off] : 0;
        __syncthreads();
        scn[tid] += t;
        __syncthreads();
    }
    int excl = scn[tid] - v;
    lbase[tid] = excl;
    int gb_ = 0;
    if (v > 0) gb_ = (int)atomicAdd(&gcur[tid], (unsigned int)v);  // v>0 => tid < nb
    gb[tid] = gb_;
    __syncthreads();

#pragma unroll
    for (int k = 0; k < 16; ++k) {
        if (myB[k] >= 0) {
            int pos = lbase[myB[k]] + myR[k];
            sbuf[pos] = myP[k];
            bbuf[pos] = (unsigned short)myB[k];
        }
    }
    __syncthreads();

    int tot = scn[MAXB - 1];
    for (int i = tid; i < tot; i += 512) {
        int b = bbuf[i];
        staged[(size_t)gb[b] + (i - lbase[b])] = sbuf[i];  // ~84B contiguous runs
    }
}

// ---------------- pass 2: per-bucket CSR fill (in-place) + dinv + row_ptr ----------------
__global__ __launch_bounds__(512) void k_fill2(
        unsigned int* __restrict__ staged,      // aliases csr output
        const int* __restrict__ bbase,
        float* __restrict__ dinv, int* __restrict__ row_ptr,
        unsigned int* __restrict__ ovf, unsigned int* __restrict__ ovfbuf,
        int N, int E, int nb) {
    __shared__ int h[NPB], scn2[NPB], lrp[NPB], cur[NPB];
    __shared__ int outb[CAP];                   // 36 KB
    __shared__ long long sOff;
    int tid = threadIdx.x;
    int b = blockIdx.x;
    int s0 = bbase[b], s1 = bbase[b + 1];
    int cnt = s1 - s0;
    int base_node = b * NPB;
    int nn = N - base_node; if (nn > NPB) nn = NPB;

    if (tid < NPB) h[tid] = 0;
    __syncthreads();
    // phase A: per-node histogram
    for (int i = tid; i < cnt; i += 512)
        atomicAdd(&h[staged[(size_t)s0 + i] & 255], 1);
    __syncthreads();
    // scan over NPB (first 256 threads)
    int hv = (tid < NPB) ? h[tid] : 0;
    if (tid < NPB) scn2[tid] = hv;
    __syncthreads();
#pragma unroll
    for (int off = 1; off < NPB; off <<= 1) {
        int t = (tid >= off && tid < NPB) ? scn2[tid - off] : 0;
        __syncthreads();
        if (tid < NPB) scn2[tid] += t;
        __syncthreads();
    }
    if (tid < NPB) {
        int excl = scn2[tid] - hv;
        lrp[tid] = excl;
        cur[tid] = excl;
    }
    // emit dinv + row_ptr
    if (tid < nn) {
        dinv[base_node + tid] = rsqrtf((float)(hv + 1));       // +1 self loop
        row_ptr[base_node + tid] = s0 + (scn2[tid] - hv);
    }
    if (b == nb - 1 && tid == 0) row_ptr[N] = E;
    __syncthreads();

    if (cnt <= CAP) {
        // phase C: scatter into LDS at final local positions
        for (int i = tid; i < cnt; i += 512) {
            unsigned int p = staged[(size_t)s0 + i];
            int pos = atomicAdd(&cur[p & 255], 1);
            outb[pos] = (int)(p >> 8);
        }
        __syncthreads();
        // phase D: coalesced stream-out (in-place over staged)
        for (int i = tid; i < cnt; i += 512)
            ((int*)staged)[(size_t)s0 + i] = outb[i];
    } else {
        // overflow path (practically unreachable): bounce via global scratch
        if (tid == 0) {
            unsigned int o = atomicAdd(ovf, (unsigned int)cnt);
            sOff = ((size_t)o + (size_t)cnt <= (size_t)OVF_CAP) ? (long long)o : -1;
        }
        __syncthreads();
        if (sOff >= 0) {
            unsigned int* scr = ovfbuf + sOff;
            for (int i = tid; i < cnt; i += 512) scr[i] = staged[(size_t)s0 + i];
            __syncthreads();
            for (int i = tid; i < cnt; i += 512) {
                unsigned int p = scr[i];
                int pos = atomicAdd(&cur[p & 255], 1);
                ((int*)staged)[(size_t)s0 + pos] = (int)(p >> 8);
            }
        }
    }
}

// ---------------- layer 1 GEMM: g1 = dinv * (x @ W1) ----------------
__global__ void k_gemm1(const float* __restrict__ x, const float* __restrict__ W1,
                        const float* __restrict__ dinv, float* __restrict__ g1, int n) {
    __shared__ float w[D_IN * D_HID];  // 8 KiB
    for (int i = threadIdx.x; i < D_IN * D_HID; i += blockDim.x)
        w[i] = W1[i];
    __syncthreads();
    int tid = blockIdx.x * blockDim.x + threadIdx.x;
    int node = tid >> 4, f = tid & 15;
    if (node >= n) return;
    const float4* xr = (const float4*)(x + (size_t)node * D_IN);
    float acc = 0.f;
#pragma unroll
    for (int k4 = 0; k4 < D_IN / 4; ++k4) {
        float4 v = xr[k4];
        int k = k4 * 4;
        acc += v.x * w[(k + 0) * D_HID + f];
        acc += v.y * w[(k + 1) * D_HID + f];
        acc += v.z * w[(k + 2) * D_HID + f];
        acc += v.w * w[(k + 3) * D_HID + f];
    }
    g1[tid] = dinv[node] * acc;
}

// ---------------- fused: gather-agg1 + bias + ReLU + GEMM2 -> g2 ----------------
__global__ void k_agg1f(const int* __restrict__ csr_src, const int* __restrict__ row_ptr,
                        const float* __restrict__ dinv, const float* __restrict__ g1,
                        const float* __restrict__ b1, const float* __restrict__ W2,
                        float2* __restrict__ g2, int n) {
    int tid = blockIdx.x * blockDim.x + threadIdx.x;
    int node = tid >> 4, f = tid & 15;
    if (node >= n) return;
    int beg = row_ptr[node], end = row_ptr[node + 1];
    float acc = g1[(size_t)node * D_HID + f];   // self-loop term
    int gbase = (threadIdx.x & 63) & 48;
    for (int j = beg; j < end; j += 16) {
        int m = end - j; if (m > 16) m = 16;
        int myS = (j + f < end) ? csr_src[j + f] : 0;
        for (int k = 0; k < m; ++k) {
            int s = __shfl(myS, gbase + k, 64);
            acc += g1[(size_t)s * D_HID + f];
        }
    }
    float di = dinv[node];
    float r = fmaxf(b1[f] + di * acc, 0.f);
    float c0 = r * W2[f * N_CLS + 0];
    float c1 = r * W2[f * N_CLS + 1];
#pragma unroll
    for (int m = 8; m >= 1; m >>= 1) {
        c0 += __shfl_xor(c0, m, 64);
        c1 += __shfl_xor(c1, m, 64);
    }
    if (f == 0) g2[node] = make_float2(di * c0, di * c1);
}

// ---------------- fused: gather-agg2 + bias + log_softmax -> out ----------------
__global__ void k_agg2lsm(const int* __restrict__ csr_src, const int* __restrict__ row_ptr,
                          const float* __restrict__ dinv, const float2* __restrict__ g2,
                          const float* __restrict__ b2, float2* __restrict__ out, int n) {
    int node = blockIdx.x * blockDim.x + threadIdx.x;
    if (node >= n) return;
    float2 self = g2[node];
    float a0 = self.x, a1 = self.y;
    int beg = row_ptr[node], end = row_ptr[node + 1];
    for (int j = beg; j < end; ++j) {
        float2 t = g2[csr_src[j]];
        a0 += t.x; a1 += t.y;
    }
    float di = dinv[node];
    float v0 = b2[0] + di * a0;
    float v1 = b2[1] + di * a1;
    float mx = fmaxf(v0, v1);
    float lse = mx + logf(expf(v0 - mx) + expf(v1 - mx));
    out[node] = make_float2(v0 - lse, v1 - lse);
}

// =================== fallback (round-3 atomic path, if ws too small) ===================
__global__ void fb_deg_init(unsigned int* __restrict__ deg, int n) {
    int i = blockIdx.x * blockDim.x + threadIdx.x;
    if (i < n) deg[i] = 1u;
}
template<bool I64>
__global__ void fb_deg_count(const void* __restrict__ ei, unsigned int* __restrict__ deg,
                             int E, const int* __restrict__ flags) {
    if (flags[FE] != (int)I64) return;
    int e = blockIdx.x * blockDim.x + threadIdx.x;
    if (e < E) atomicAdd(&deg[lde<I64>(ei, (size_t)E + e)], 1u);
}
__global__ void fb_dinv_inplace(float* __restrict__ dinv, int n) {
    int i = blockIdx.x * blockDim.x + threadIdx.x;
    if (i < n) {
        unsigned int u = ((const unsigned int*)dinv)[i];
        dinv[i] = rsqrtf((float)u);
    }
}
__global__ void fb_a1_init(const float* __restrict__ h1, const float* __restrict__ dinv,
                           const float* __restrict__ b1, float* __restrict__ a1, int n) {
    int tid = blockIdx.x * blockDim.x + threadIdx.x;
    if (tid >= n * D_HID) return;
    int node = tid >> 4, f = tid & 15;
    float di = dinv[node];
    a1[tid] = b1[f] + di * di * h1[tid];
}
template<bool I64>
__global__ void fb_agg1(const void* __restrict__ ei, const float* __restrict__ dinv,
                        const float* __restrict__ h1, float* __restrict__ a1,
                        int E, const int* __restrict__ flags) {
    if (flags[FE] != (int)I64) return;
    int tid = blockIdx.x * blockDim.x + threadIdx.x;
    int e = tid >> 4, f = tid & 15;
    if (e >= E) return;
    int s = lde<I64>(ei, (size_t)e);
    int d = lde<I64>(ei, (size_t)E + e);
    float norm = dinv[s] * dinv[d];
    atomicAdd(&a1[(size_t)d * D_HID + f], h1[(size_t)s * D_HID + f] * norm);
}
__global__ void fb_relu_gemm2(const float* __restrict__ a1, const float* __restrict__ W2,
                              float* __restrict__ h2, int n) {
    int node = blockIdx.x * blockDim.x + threadIdx.x;
    if (node >= n) return;
    float c0 = 0.f, c1 = 0.f;
    const float* row = a1 + (size_t)node * D_HID;
#pragma unroll
    for (int f = 0; f < D_HID; ++f) {
        float r = fmaxf(row[f], 0.f);
        c0 += r * W2[f * N_CLS + 0];
        c1 += r * W2[f * N_CLS + 1];
    }
    h2[(size_t)node * 2 + 0] = c0;
    h2[(size_t)node * 2 + 1] = c1;
}
__global__ void fb_a2_init(const float* __restrict__ h2, const float* __restrict__ dinv,
                           const float* __restrict__ b2, float* __restrict__ a2, int n) {
    int tid = blockIdx.x * blockDim.x + threadIdx.x;
    if (tid >= n * N_CLS) return;
    int node = tid >> 1, c = tid & 1;
    float di = dinv[node];
    a2[tid] = b2[c] + di * di * h2[tid];
}
template<bool I64>
__global__ void fb_agg2(const void* __restrict__ ei, const float* __restrict__ dinv,
                        const float* __restrict__ h2, float* __restrict__ a2,
                        int E, const int* __restrict__ flags) {
    if (flags[FE] != (int)I64) return;
    int e = blockIdx.x * blockDim.x + threadIdx.x;
    if (e >= E) return;
    int s = lde<I64>(ei, (size_t)e);
    int d = lde<I64>(ei, (size_t)E + e);
    float norm = dinv[s] * dinv[d];
    atomicAdd(&a2[(size_t)d * 2 + 0], h2[(size_t)s * 2 + 0] * norm);
    atomicAdd(&a2[(size_t)d * 2 + 1], h2[(size_t)s * 2 + 1] * norm);
}
__global__ void fb_gemm1(const float* __restrict__ x, const float* __restrict__ W1,
                         float* __restrict__ h1, int n) {
    __shared__ float w[D_IN * D_HID];
    for (int i = threadIdx.x; i < D_IN * D_HID; i += blockDim.x) w[i] = W1[i];
    __syncthreads();
    int tid = blockIdx.x * blockDim.x + threadIdx.x;
    int node = tid >> 4, f = tid & 15;
    if (node >= n) return;
    const float4* xr = (const float4*)(x + (size_t)node * D_IN);
    float acc = 0.f;
#pragma unroll
    for (int k4 = 0; k4 < D_IN / 4; ++k4) {
        float4 v = xr[k4];
        int k = k4 * 4;
        acc += v.x * w[(k + 0) * D_HID + f];
        acc += v.y * w[(k + 1) * D_HID + f];
        acc += v.z * w[(k + 2) * D_HID + f];
        acc += v.w * w[(k + 3) * D_HID + f];
    }
    h1[tid] = acc;
}
__global__ void fb_lsm(const float* __restrict__ a2, float* __restrict__ out, int n) {
    int node = blockIdx.x * blockDim.x + threadIdx.x;
    if (node >= n) return;
    float v0 = a2[(size_t)node * 2 + 0];
    float v1 = a2[(size_t)node * 2 + 1];
    float m = fmaxf(v0, v1);
    float lse = m + logf(expf(v0 - m) + expf(v1 - m));
    out[(size_t)node * 2 + 0] = v0 - lse;
    out[(size_t)node * 2 + 1] = v1 - lse;
}

extern "C" void kernel_launch(void* const* d_in, const int* in_sizes, int n_in,
                              void* d_out, int out_size, void* d_ws, size_t ws_size,
                              hipStream_t stream) {
    const float* x  = (const float*)d_in[0];
    const void*  ei = d_in[1];
    const float* W1 = (const float*)d_in[2];
    const float* b1 = (const float*)d_in[3];
    const float* W2 = (const float*)d_in[4];
    const float* b2 = (const float*)d_in[5];

    const int N = in_sizes[0] / D_IN;      // 100000
    const int E = in_sizes[1] / 2;         // 3200000
    const int nb = (N + NPB - 1) / NPB;    // 391

    const int B = 256;
    dim3 blk(B);
    const int nBlkN = (N + B - 1) / B;
    const int nBlkE = (E + B - 1) / B;
    char* ws = (char*)d_ws;

    // ---- tight workspace layout (must fit proven ws_size >= 20,804,736) ----
    const size_t oDinv  = 0;                                   // N f32
    const size_t oRow   = (size_t)N * 4;                       // (N+1) int
    const size_t oGBcnt = oRow + (size_t)(N + 1) * 4;          // nb u32
    const size_t oOvf   = oGBcnt + (size_t)nb * 4;             // 1 u32
    const size_t oBB    = oOvf + 4;                            // (nb+1) int
    const size_t oGcur  = oBB + (size_t)(nb + 1) * 4;          // nb u32
    const size_t oFlag  = oGcur + (size_t)nb * 4;              // 2 int
    const size_t oStage = (oFlag + 8 + 15) & ~(size_t)15;      // E u32 (later: csr_src)
    const size_t oG1    = oStage + (size_t)E * 4;              // N*16 f32 (also ovf scratch)
    const size_t oG2    = oG1 + (size_t)N * D_HID * 4;         // N*2 f32
    const size_t needNew = oG2 + (size_t)N * 2 * 4;

    if (ws_size >= needNew && nb <= MAXB) {
        float*        dinv    = (float*)(ws + oDinv);
        int*          row_ptr = (int*)(ws + oRow);
        unsigned int* gbcnt   = (unsigned int*)(ws + oGBcnt);
        unsigned int* ovf     = (unsigned int*)(ws + oOvf);
        int*          bbase   = (int*)(ws + oBB);
        unsigned int* gcur    = (unsigned int*)(ws + oGcur);
        int*          flags   = (int*)(ws + oFlag);
        unsigned int* staged  = (unsigned int*)(ws + oStage);  // becomes csr_src in-place
        float*        g1      = (float*)(ws + oG1);
        float2*       g2      = (float2*)(ws + oG2);
        int*          csr_src = (int*)staged;

        k_detect<<<dim3(1), blk, 0, stream>>>((const int*)ei, flags);
        hipMemsetAsync(gbcnt, 0, (size_t)nb * 4 + 4, stream);  // gbcnt + ovf

        k_bhist<false><<<dim3(256), blk, 0, stream>>>(ei, gbcnt, E, flags);
        k_bhist<true ><<<dim3(256), blk, 0, stream>>>(ei, gbcnt, E, flags);
        k_bscan<<<dim3(1), dim3(MAXB), 0, stream>>>(gbcnt, bbase, gcur, nb);

        dim3 gPart((E + TILE - 1) / TILE);
        k_part<false><<<gPart, dim3(512), 0, stream>>>(ei, gcur, staged, E, flags);
        k_part<true ><<<gPart, dim3(512), 0, stream>>>(ei, gcur, staged, E, flags);

        k_fill2<<<dim3(nb), dim3(512), 0, stream>>>(staged, bbase, dinv, row_ptr,
                                                    ovf, (unsigned int*)g1, N, E, nb);

        dim3 g_nh((N * D_HID + B - 1) / B);
        k_gemm1<<<g_nh, blk, 0, stream>>>(x, W1, dinv, g1, N);
        k_agg1f<<<g_nh, blk, 0, stream>>>(csr_src, row_ptr, dinv, g1, b1, W2, g2, N);
        k_agg2lsm<<<dim3(nBlkN), blk, 0, stream>>>(csr_src, row_ptr, dinv, g2, b2,
                                                   (float2*)d_out, N);
    } else {
        // fallback: round-3 atomic path (needs ~14.8 MB)
        float* dinv  = (float*)(ws + 0);
        float* h1    = (float*)(ws + 400128);
        float* a1    = (float*)(ws + 6800256);
        float* h2    = (float*)(ws + 13200384);
        float* a2    = (float*)(ws + 14000512);
        int*   flags = (int*)  (ws + 14800640);

        k_detect<<<dim3(1), blk, 0, stream>>>((const int*)ei, flags);
        fb_deg_init<<<dim3(nBlkN), blk, 0, stream>>>((unsigned int*)dinv, N);
        fb_deg_count<false><<<dim3(nBlkE), blk, 0, stream>>>(ei, (unsigned int*)dinv, E, flags);
        fb_deg_count<true ><<<dim3(nBlkE), blk, 0, stream>>>(ei, (unsigned int*)dinv, E, flags);
        fb_dinv_inplace<<<dim3(nBlkN), blk, 0, stream>>>(dinv, N);

        dim3 g_nh((N * D_HID + B - 1) / B);
        fb_gemm1<<<g_nh, blk, 0, stream>>>(x, W1, h1, N);
        fb_a1_init<<<g_nh, blk, 0, stream>>>(h1, dinv, b1, a1, N);
        dim3 g_eh(((size_t)E * D_HID + B - 1) / B);
        fb_agg1<false><<<g_eh, blk, 0, stream>>>(ei, dinv, h1, a1, E, flags);
        fb_agg1<true ><<<g_eh, blk, 0, stream>>>(ei, dinv, h1, a1, E, flags);
        fb_relu_gemm2<<<dim3(nBlkN), blk, 0, stream>>>(a1, W2, h2, N);
        dim3 g_n2((N * N_CLS + B - 1) / B);
        fb_a2_init<<<g_n2, blk, 0, stream>>>(h2, dinv, b2, a2, N);
        fb_agg2<false><<<dim3(nBlkE), blk, 0, stream>>>(ei, dinv, h2, a2, E, flags);
        fb_agg2<true ><<<dim3(nBlkE), blk, 0, stream>>>(ei, dinv, h2, a2, E, flags);
        fb_lsm<<<dim3(nBlkN), blk, 0, stream>>>(a2, (float*)d_out, N);
    }
}